// Round 5
// baseline (4810.011 us; speedup 1.0000x reference)
//
#include <hip/hip_runtime.h>
#include <math.h>
#include <stdint.h>

#define BB 32
#define TT 2048
#define FF 128
#define HH 512
#define FCC 128
#define QW 8      // workgroups per batch
#define RPW 64    // hidden rows per WG
#define NTH 512   // threads per WG

// LDS pad: +4 words per 64 -> the 8 c-chunk b128 streams hit disjoint banks
__device__ __forceinline__ int hpad(int i) { return i + ((i >> 6) << 2); }

// barrier WITHOUT vmcnt drain: LDS ordering only. Global ops in flight
// (x prefetch, publish store) are NOT drained; compiler auto-waits before use.
__device__ __forceinline__ void barrier_lgkm() {
    asm volatile("s_waitcnt lgkmcnt(0)\n\ts_barrier" ::: "memory");
}

__device__ __forceinline__ float fast_tanh(float z) {
    float ax = fabsf(z);
    float e  = __expf(-2.0f * ax);          // v_exp_f32 path, branchless
    float r  = (1.0f - e) / (1.0f + e);
    return copysignf(r, z);
}

__global__ void ws_zero(uint64_t* g) {
    g[(size_t)blockIdx.x * blockDim.x + threadIdx.x] = 0ull;
}

// grid = 256 blocks (1/CU, co-resident).
// b = blk & 31, q = blk >> 5  =>  blk % 8 == b % 8: under round-robin
// block->XCD dispatch all 8 WGs of batch b share one XCD, so the h-exchange
// (agent-scope tagged u64 atomics) stays in that XCD's L2 (~200cyc RT)
// instead of round-tripping the Infinity Cache. (Perf heuristic only —
// correctness never depends on placement.)
// Thread (row=tid>>3, c=tid&7): rows q*64+row, cols [c*64,c*64+64) of W_hh in
// 16 named float4 VGPRs. Per step:
//   - deferred scorer (q==0): score h_i from synced LDS, overlaps matvec
//   - matvec acc = xacc_i + W_hh[chunk].h_i ; 3-shfl reduce
//   - c==0: fast_tanh, own h -> LDS direct + tagged u64 publish
//   - xacc_{i+1} = W_ih.x_{i+1} from regs loaded a full step ago (no vm wait)
//   - pollers (tid<128, skip own q): 4 pipelined tagged loads, stage to LDS
//   - prefetch x_{i+2} AFTER poll (overlaps barrier + next matvec)
//   - ONE lgkm-only barrier
__global__ __launch_bounds__(NTH, 1)
void rnn_seq(const float* __restrict__ x, const int* __restrict__ lengths,
             const float* __restrict__ W_ih, const float* __restrict__ W_hh,
             const float* __restrict__ b_ih, const float* __restrict__ b_hh,
             const float* __restrict__ W1, const float* __restrict__ b1,
             const float* __restrict__ W2, const float* __restrict__ b2,
             float* __restrict__ out, uint64_t* __restrict__ gbuf)
{
    const int blk = blockIdx.x;
    const int b   = blk & 31;       // batch (same-XCD grouping)
    const int q   = blk >> 5;       // row slice
    const int tid = threadIdx.x;
    const int row = tid >> 3;
    const int c   = tid & 7;
    const int grow = q * RPW + row;
    const int len = lengths[b];

    __shared__ float hsA[HH + 32];
    __shared__ float hsB[HH + 32];
    __shared__ float red[2][2];

    // ---- W_hh slice: 16 named float4s (VGPR/AGPR-resident) ----
    const float4* wp = (const float4*)(W_hh + (size_t)grow * HH + c * 64);
    float4 ww0 = wp[0],  ww1 = wp[1],  ww2 = wp[2],  ww3 = wp[3];
    float4 ww4 = wp[4],  ww5 = wp[5],  ww6 = wp[6],  ww7 = wp[7];
    float4 ww8 = wp[8],  ww9 = wp[9],  ww10 = wp[10], ww11 = wp[11];
    float4 ww12 = wp[12], ww13 = wp[13], ww14 = wp[14], ww15 = wp[15];

    const float4* wip = (const float4*)(W_ih + grow * FF + c * 16);
    float4 wi0 = wip[0], wi1 = wip[1], wi2 = wip[2], wi3 = wip[3];

    const float bias_r = b_ih[grow] + b_hh[grow];

    // fused scorer: wvr = (W2 @ W1)[4t..4t+3];  cconst = W2@b1 + b2
    float4 wvr = make_float4(0.f, 0.f, 0.f, 0.f);
    if (tid < 128) {
        for (int f = 0; f < FCC; ++f) {
            float w2 = W2[f];
            const float* w1 = W1 + f * HH + tid * 4;
            wvr.x += w2 * w1[0]; wvr.y += w2 * w1[1];
            wvr.z += w2 * w1[2]; wvr.w += w2 * w1[3];
        }
    }
    float cconst = 0.f;
    if (q == 0 && tid == 0) {
        float a = 0.f;
        for (int f = 0; f < FCC; ++f) a += W2[f] * b1[f];
        cconst = a + b2[0];
    }

    hsA[hpad(tid)] = 0.0f;
    __syncthreads();                 // one-time full barrier (hsA init)

    const float* xb = x + (size_t)b * TT * FF + c * 16;
    float4 ra0, ra1, ra2, ra3, rb0, rb1, rb2, rb3;
    { const float4* p = (const float4*)(xb);              ra0 = p[0]; ra1 = p[1]; ra2 = p[2]; ra3 = p[3]; }
    { const float4* p = (const float4*)(xb + (size_t)FF); rb0 = p[0]; rb1 = p[1]; rb2 = p[2]; rb3 = p[3]; }

    uint64_t* slot0 = gbuf + (size_t)b * HH;
    uint64_t* slot1 = gbuf + (size_t)(BB + b) * HH;

    const int sc_off = tid * 4 + ((tid >> 4) << 2);   // hpad(4*tid)
    const bool is_poller = (tid < 128) && ((tid >> 4) != q);
    const bool is_scorer = (q == 0) && (tid < 128);

    // xacc for step 0 from ra (x_0); ra then becomes the prefetch target
    float xaccA = wi0.x*ra0.x + wi0.y*ra0.y + wi0.z*ra0.z + wi0.w*ra0.w
                + wi1.x*ra1.x + wi1.y*ra1.y + wi1.z*ra1.z + wi1.w*ra1.w
                + wi2.x*ra2.x + wi2.y*ra2.y + wi2.z*ra2.z + wi2.w*ra2.w
                + wi3.x*ra3.x + wi3.y*ra3.y + wi3.z*ra3.z + wi3.w*ra3.w;
    float xaccB = 0.0f;

    int count = 0;

#define MV4(K) { float4 hk = hq[K]; \
    a0 += ww##K.x * hk.x; a1 += ww##K.y * hk.y; \
    a2 += ww##K.z * hk.z; a3 += ww##K.w * hk.w; }

#define STEP(I, HCUR, HNXT, XCUR, XNXT, RN0,RN1,RN2,RN3, RL0,RL1,RL2,RL3)       \
  {                                                                             \
    /* deferred scorer on h_I (synced in HCUR last barrier) — overlaps matvec */\
    if (is_scorer && (I) > 0) {                                                 \
      float4 hv = *(const float4*)(HCUR + sc_off);                              \
      float p2 = hv.x * wvr.x + hv.y * wvr.y + hv.z * wvr.z + hv.w * wvr.w;     \
      p2 += __shfl_xor(p2, 1);  p2 += __shfl_xor(p2, 2);                        \
      p2 += __shfl_xor(p2, 4);  p2 += __shfl_xor(p2, 8);                        \
      p2 += __shfl_xor(p2, 16); p2 += __shfl_xor(p2, 32);                       \
      if ((tid & 63) == 0) red[(I) & 1][tid >> 6] = p2;                         \
    }                                                                           \
    const float4* hq = (const float4*)(HCUR + c * 68);                          \
    float a0 = XCUR, a1 = 0.f, a2 = 0.f, a3 = 0.f;                              \
    MV4(0)  MV4(1)  MV4(2)  MV4(3)  MV4(4)  MV4(5)  MV4(6)  MV4(7)             \
    MV4(8)  MV4(9)  MV4(10) MV4(11) MV4(12) MV4(13) MV4(14) MV4(15)            \
    float acc = (a0 + a1) + (a2 + a3);                                          \
    acc += __shfl_xor(acc, 1);                                                  \
    acc += __shfl_xor(acc, 2);                                                  \
    acc += __shfl_xor(acc, 4);                                                  \
    uint64_t* sw = ((I) & 1) ? slot1 : slot0;                                   \
    if (c == 0) {                                                               \
      float hn = fast_tanh(acc + bias_r);                                       \
      HNXT[hpad(grow)] = hn;                      /* own slice -> LDS direct */ \
      uint64_t pk = ((uint64_t)(uint32_t)((I) + 1) << 32) |                     \
                    (uint64_t)__float_as_uint(hn);                              \
      __hip_atomic_store(&sw[grow], pk, __ATOMIC_RELAXED,                       \
                         __HIP_MEMORY_SCOPE_AGENT);                             \
    }                                                                           \
    /* W_ih . x_{I+1}: RN regs were loaded a full step ago — no vm wait */      \
    XNXT = wi0.x*RN0.x + wi0.y*RN0.y + wi0.z*RN0.z + wi0.w*RN0.w               \
         + wi1.x*RN1.x + wi1.y*RN1.y + wi1.z*RN1.z + wi1.w*RN1.w               \
         + wi2.x*RN2.x + wi2.y*RN2.y + wi2.z*RN2.z + wi2.w*RN2.w               \
         + wi3.x*RN3.x + wi3.y*RN3.y + wi3.z*RN3.z + wi3.w*RN3.w;              \
    if (is_poller) {                                                            \
      const uint64_t tg = (uint64_t)(uint32_t)((I) + 1);                        \
      uint64_t* pr = sw + tid * 4;                                              \
      uint64_t u0, u1, u2, u3;                                                  \
      do {                                                                      \
        u0 = __hip_atomic_load(pr + 0, __ATOMIC_RELAXED, __HIP_MEMORY_SCOPE_AGENT); \
        u1 = __hip_atomic_load(pr + 1, __ATOMIC_RELAXED, __HIP_MEMORY_SCOPE_AGENT); \
        u2 = __hip_atomic_load(pr + 2, __ATOMIC_RELAXED, __HIP_MEMORY_SCOPE_AGENT); \
        u3 = __hip_atomic_load(pr + 3, __ATOMIC_RELAXED, __HIP_MEMORY_SCOPE_AGENT); \
      } while ((u0 >> 32) != tg || (u1 >> 32) != tg ||                          \
               (u2 >> 32) != tg || (u3 >> 32) != tg);                           \
      float4 hv = make_float4(__uint_as_float((uint32_t)u0),                    \
                              __uint_as_float((uint32_t)u1),                    \
                              __uint_as_float((uint32_t)u2),                    \
                              __uint_as_float((uint32_t)u3));                   \
      *(float4*)(HNXT + sc_off) = hv;                                           \
    }                                                                           \
    /* prefetch x_{I+2} AFTER poll: overlaps barrier + next matvec */           \
    { int tp = (I) + 2;                                                         \
      if (tp < len) { const float4* p = (const float4*)(xb + (size_t)tp * FF);  \
        RL0 = p[0]; RL1 = p[1]; RL2 = p[2]; RL3 = p[3]; } }                     \
    barrier_lgkm();                                                             \
    if (is_scorer && tid == 0 && (I) > 0) {                                     \
      float s = cconst + red[(I) & 1][0] + red[(I) & 1][1];                     \
      if (s > 0.0f) ++count;                                                    \
    }                                                                           \
  }

    int i = 0;
    for (;;) {
        STEP(i, hsA, hsB, xaccA, xaccB, rb0,rb1,rb2,rb3, ra0,ra1,ra2,ra3);
        if (++i >= len) break;
        STEP(i, hsB, hsA, xaccB, xaccA, ra0,ra1,ra2,ra3, rb0,rb1,rb2,rb3);
        if (++i >= len) break;
    }

    // ---- final score on h_len + outputs (q==0 block; conditions WG-uniform)
    if (q == 0) {
        const float* hf = (len & 1) ? hsB : hsA;   // buffer holding h_len
        const int fi = len & 1;                    // disjoint from last red read
        if (tid < 128) {
            float4 hv = *(const float4*)(hf + sc_off);
            float p2 = hv.x * wvr.x + hv.y * wvr.y + hv.z * wvr.z + hv.w * wvr.w;
            p2 += __shfl_xor(p2, 1);  p2 += __shfl_xor(p2, 2);
            p2 += __shfl_xor(p2, 4);  p2 += __shfl_xor(p2, 8);
            p2 += __shfl_xor(p2, 16); p2 += __shfl_xor(p2, 32);
            if ((tid & 63) == 0) red[fi][tid >> 6] = p2;
        }
        barrier_lgkm();
        if (tid == 0) {
            float s = cconst + red[fi][0] + red[fi][1];
            if (s > 0.0f) ++count;
            out[b] = (float)count;
        }
        out[BB + b * HH + tid] = hf[hpad(tid)];
    }
}

extern "C" void kernel_launch(void* const* d_in, const int* in_sizes, int n_in,
                              void* d_out, int out_size, void* d_ws, size_t ws_size,
                              hipStream_t stream) {
    const float* x    = (const float*)d_in[0];
    const int*   lens = (const int*)d_in[1];
    const float* W_ih = (const float*)d_in[2];
    const float* W_hh = (const float*)d_in[3];
    const float* b_ih = (const float*)d_in[4];
    const float* b_hh = (const float*)d_in[5];
    const float* W1   = (const float*)d_in[6];
    const float* b1   = (const float*)d_in[7];
    const float* W2   = (const float*)d_in[8];
    const float* b2   = (const float*)d_in[9];
    float* out = (float*)d_out;
    uint64_t* gbuf = (uint64_t*)d_ws;   // 2 * 32 * 512 u64 = 256 KB

    ws_zero<<<dim3((2 * BB * HH) / 256), dim3(256), 0, stream>>>(gbuf);
    rnn_seq<<<dim3(BB * QW), dim3(NTH), 0, stream>>>(
        x, lens, W_ih, W_hh, b_ih, b_hh, W1, b1, W2, b2, out, gbuf);
}

// Round 6
// 4036.492 us; speedup vs baseline: 1.1916x; 1.1916x over previous
//
#include <hip/hip_runtime.h>
#include <math.h>
#include <stdint.h>

#define BB 32
#define TT 2048
#define FF 128
#define HH 512
#define FCC 128
#define QW 8      // workgroups per batch
#define NTH 512   // 8 waves; wave w owns h-chunk w (64 cols) for all 64 rows

__global__ void ws_zero(uint64_t* g) {
    g[(size_t)blockIdx.x * blockDim.x + threadIdx.x] = 0ull;
}

__device__ __forceinline__ void wait_lgkm0() {
    asm volatile("s_waitcnt lgkmcnt(0)" ::: "memory");
}

__device__ __forceinline__ float fast_tanh(float z) {
    float ax = fabsf(z);
    float e  = __expf(-2.0f * ax);
    float r  = (1.0f - e) / (1.0f + e);
    return copysignf(r, z);
}

// Barrier-free pipelined RNN. grid=256 blocks (1/CU), b=blk>>3 (spread
// mapping — empirically best R2/R4), q=blk&7 = row slice (rows q*64..+64).
// Wave w (=tid>>6), lane (=tid&63):
//  - lane holds W_hh[q*64+lane][w*64..+64] (16 float4) and W_ih[.., w*16..+16]
//  - step i: wave w polls slice w of h_i (tagged u64, 1 slot/lane), stages to
//    LDS chunk, broadcast-reads back, computes per-row partials -> part[]
//  - LDS counter: last wave finalizes (sum 8 partials + bias, tanh, publish
//    h_{i+1} global + own chunk to LDS + step-flag). No __syncthreads in loop.
//  - 2-deep buffers safe: any wave's detect(i) implies local finalize(i-2)
//    (publish->poll causality through remote WGs bounds skew to 1 step).
//  - scorer (WG q==0 only): chunk dot vs wv=W2@W1 from in-register staged
//    values; finalizer sums sdot[8] + cconst, counts in LDS.
__global__ __launch_bounds__(NTH, 1)
void rnn_seq(const float* __restrict__ x, const int* __restrict__ lengths,
             const float* __restrict__ W_ih, const float* __restrict__ W_hh,
             const float* __restrict__ b_ih, const float* __restrict__ b_hh,
             const float* __restrict__ W1, const float* __restrict__ b1,
             const float* __restrict__ W2, const float* __restrict__ b2,
             float* __restrict__ out, uint64_t* __restrict__ gbuf)
{
    const int blk  = blockIdx.x;
    const int b    = blk >> 3;      // batch (spread mapping)
    const int q    = blk & 7;       // row slice
    const int tid  = threadIdx.x;
    const int w    = tid >> 6;      // wave id = h-chunk id
    const int lane = tid & 63;      // row within slice
    const int grow = q * 64 + lane;
    const int len  = lengths[b];

    __shared__ float hs[2][8 * 68];       // [parity][chunk*68 + j], 4-word pad
    __shared__ float part[2][64 * 9 + 8]; // [parity][row*9 + w]
    __shared__ float sdot[2][8];
    __shared__ float wvs[HH];
    __shared__ float biass[64];
    __shared__ int   cnt_s, cnt2_s, flag_s;
    __shared__ float cconst_s;

    // ---- register-resident weights ----
    float4 ww[16];
    { const float4* p = (const float4*)(W_hh + (size_t)grow * HH + w * 64);
      #pragma unroll
      for (int k = 0; k < 16; ++k) ww[k] = p[k]; }
    float4 wi[4];
    { const float4* p = (const float4*)(W_ih + grow * FF + w * 16);
      #pragma unroll
      for (int k = 0; k < 4; ++k) wi[k] = p[k]; }

    if (w == 0) biass[lane] = b_ih[grow] + b_hh[grow];
    { float a = 0.0f;
      #pragma unroll 8
      for (int f = 0; f < FCC; ++f) a += W2[f] * W1[f * HH + tid];
      wvs[tid] = a; }
    if (tid == 0) {
        float a = 0.0f;
        for (int f = 0; f < FCC; ++f) a += W2[f] * b1[f];
        cconst_s = a + b2[0];
        cnt_s = 0; cnt2_s = 0; flag_s = 0;
    }
    hs[0][w * 68 + lane] = 0.0f;          // h_0 = 0

    // x broadcast (wave-uniform 16 floats per wave), register double-buffer
    const float* xb = x + (size_t)b * TT * FF + w * 16;
    float4 xc[4], xn[4];
    { const float4* p = (const float4*)xb;
      #pragma unroll
      for (int k = 0; k < 4; ++k) xc[k] = p[k]; }
    { const float4* p = (const float4*)(xb + FF);   // x_1 (in-bounds: T rows)
      #pragma unroll
      for (int k = 0; k < 4; ++k) xn[k] = p[k]; }

    __syncthreads();   // one-time: init visible

    uint64_t* gs0 = gbuf + (size_t)b * HH;          // even-parity slots
    uint64_t* gs1 = gbuf + (size_t)(BB + b) * HH;   // odd-parity slots

    for (int i = 0; i < len; ++i) {
        const int p  = i & 1;
        const int pn = p ^ 1;
        uint64_t* gsp  = p  ? gs1 : gs0;
        uint64_t* gspn = pn ? gs1 : gs0;

        if (i > 0) {
            if (w != q) {
                // poll slice w of h_i (remote WG published tag i)
                uint64_t* pr = gsp + w * 64 + lane;
                uint64_t u;
                do { u = __hip_atomic_load(pr, __ATOMIC_RELAXED,
                                           __HIP_MEMORY_SCOPE_AGENT); }
                while ((int)(u >> 32) != i);
                hs[p][w * 68 + lane] = __uint_as_float((uint32_t)u);
                wait_lgkm0();           // staged before broadcast readback
            } else {
                // own chunk written by local finalize(i-1)
                while (__hip_atomic_load(&flag_s, __ATOMIC_RELAXED,
                                         __HIP_MEMORY_SCOPE_WORKGROUP) < i) {}
            }
        }

        // ---- chunk matvec: partial for row=lane over cols w*64..w*64+64
        const float4* hq = (const float4*)&hs[p][w * 68];
        float a0, a1, a2, a3;
        a0 = wi[0].x*xc[0].x + wi[0].y*xc[0].y + wi[0].z*xc[0].z + wi[0].w*xc[0].w;
        a1 = wi[1].x*xc[1].x + wi[1].y*xc[1].y + wi[1].z*xc[1].z + wi[1].w*xc[1].w;
        a2 = wi[2].x*xc[2].x + wi[2].y*xc[2].y + wi[2].z*xc[2].z + wi[2].w*xc[2].w;
        a3 = wi[3].x*xc[3].x + wi[3].y*xc[3].y + wi[3].z*xc[3].z + wi[3].w*xc[3].w;
        #pragma unroll
        for (int k = 0; k < 16; ++k) {
            float4 hk = hq[k];
            a0 += ww[k].x * hk.x; a1 += ww[k].y * hk.y;
            a2 += ww[k].z * hk.z; a3 += ww[k].w * hk.w;
        }
        float acc = (a0 + a1) + (a2 + a3);

        // ---- WG0: chunk dot for the fused scorer (h_i . wv), i>=1
        if (q == 0 && i > 0) {
            const float4* wq4 = (const float4*)&wvs[w * 64];
            float d0 = 0.f, d1 = 0.f;
            #pragma unroll
            for (int k = 0; k < 16; ++k) {
                float4 hk = hq[k]; float4 wk = wq4[k];
                d0 += hk.x * wk.x + hk.y * wk.y;
                d1 += hk.z * wk.z + hk.w * wk.w;
            }
            if (lane == 0) sdot[p][w] = d0 + d1;
        }

        part[p][lane * 9 + w] = acc;
        wait_lgkm0();                      // partial (+sdot) visible pre-count
        int old = 0;
        if (lane == 0) old = atomicAdd(&cnt_s, 1);
        old = __shfl(old, 0);

        // rotate x regs; prefetch x_{i+2} (off critical path)
        #pragma unroll
        for (int k = 0; k < 4; ++k) xc[k] = xn[k];
        if (i + 2 < len) {
            const float4* p4 = (const float4*)(xb + (size_t)(i + 2) * FF);
            #pragma unroll
            for (int k = 0; k < 4; ++k) xn[k] = p4[k];
        }

        if (old == 8 * i + 7) {
            // ---- finalize (last wave): h_{i+1} for own 64 rows
            float s8 = biass[lane];
            #pragma unroll
            for (int k = 0; k < 8; ++k) s8 += part[p][lane * 9 + k];
            float hn = fast_tanh(s8);
            uint64_t pk = ((uint64_t)(uint32_t)(i + 1) << 32) |
                          (uint64_t)__float_as_uint(hn);
            __hip_atomic_store(gspn + grow, pk, __ATOMIC_RELAXED,
                               __HIP_MEMORY_SCOPE_AGENT);   // publish ASAP
            if (q == 0 && i > 0 && lane == 0) {
                float ss = cconst_s;
                #pragma unroll
                for (int k = 0; k < 8; ++k) ss += sdot[p][k];
                if (ss > 0.0f) cnt2_s = cnt2_s + 1;   // unique writer per step
            }
            hs[pn][q * 68 + lane] = hn;               // own chunk for step i+1
            wait_lgkm0();
            if (lane == 0)
                __hip_atomic_store(&flag_s, i + 1, __ATOMIC_RELAXED,
                                   __HIP_MEMORY_SCOPE_WORKGROUP);
        }
    }

    // ---- outputs (WG q==0 only): h_len published with tag=len
    if (q == 0) {
        uint64_t* gsf = (len & 1) ? gs1 : gs0;
        while (__hip_atomic_load(&flag_s, __ATOMIC_RELAXED,
                                 __HIP_MEMORY_SCOPE_WORKGROUP) < len) {}
        if (w == 0) {
            // full h_len: lane j holds h[j + 64k], k=0..7
            uint64_t u[8]; bool ok;
            do {
                ok = true;
                #pragma unroll
                for (int k = 0; k < 8; ++k)
                    u[k] = __hip_atomic_load(gsf + lane + 64 * k,
                                             __ATOMIC_RELAXED,
                                             __HIP_MEMORY_SCOPE_AGENT);
                #pragma unroll
                for (int k = 0; k < 8; ++k) ok &= ((int)(u[k] >> 32) == len);
            } while (!ok);
            out[BB + b * HH + lane] = __uint_as_float((uint32_t)u[0]); // slice0
            float sacc = 0.0f;
            #pragma unroll
            for (int k = 0; k < 8; ++k)
                sacc += __uint_as_float((uint32_t)u[k]) * wvs[lane + 64 * k];
            #pragma unroll
            for (int off = 32; off; off >>= 1) sacc += __shfl_xor(sacc, off);
            if (lane == 0) {
                float ss = sacc + cconst_s;
                int tot = cnt2_s + (ss > 0.0f ? 1 : 0);
                out[b] = (float)tot;
            }
        } else {
            uint64_t* pr = gsf + w * 64 + lane;
            uint64_t u;
            do { u = __hip_atomic_load(pr, __ATOMIC_RELAXED,
                                       __HIP_MEMORY_SCOPE_AGENT); }
            while ((int)(u >> 32) != len);
            out[BB + b * HH + w * 64 + lane] = __uint_as_float((uint32_t)u);
        }
    }
}

extern "C" void kernel_launch(void* const* d_in, const int* in_sizes, int n_in,
                              void* d_out, int out_size, void* d_ws, size_t ws_size,
                              hipStream_t stream) {
    const float* x    = (const float*)d_in[0];
    const int*   lens = (const int*)d_in[1];
    const float* W_ih = (const float*)d_in[2];
    const float* W_hh = (const float*)d_in[3];
    const float* b_ih = (const float*)d_in[4];
    const float* b_hh = (const float*)d_in[5];
    const float* W1   = (const float*)d_in[6];
    const float* b1   = (const float*)d_in[7];
    const float* W2   = (const float*)d_in[8];
    const float* b2   = (const float*)d_in[9];
    float* out = (float*)d_out;
    uint64_t* gbuf = (uint64_t*)d_ws;   // 2 * 32 * 512 u64 = 256 KB

    ws_zero<<<dim3((2 * BB * HH) / 256), dim3(256), 0, stream>>>(gbuf);
    rnn_seq<<<dim3(BB * QW), dim3(NTH), 0, stream>>>(
        x, lens, W_ih, W_hh, b_ih, b_hh, W1, b1, W2, b2, out, gbuf);
}

// Round 7
// 3175.508 us; speedup vs baseline: 1.5147x; 1.2711x over previous
//
#include <hip/hip_runtime.h>
#include <math.h>
#include <stdint.h>

#define BB 32
#define TT 2048
#define FF 128
#define HH 512
#define FCC 128
#define QW 8
#define NTH 576   // 9 waves: 0-6 poll+compute, 7 compute+finalize+publish, 8 x-loader

__global__ void ws_zero(uint64_t* g) {
    g[(size_t)blockIdx.x * blockDim.x + threadIdx.x] = 0ull;
}

__device__ __forceinline__ void wait_lgkm0() {
    asm volatile("s_waitcnt lgkmcnt(0)" ::: "memory");
}

__device__ __forceinline__ float fast_tanh(float z) {
    float ax = fabsf(z);
    float e  = __expf(-2.0f * ax);
    float r  = (1.0f - e) / (1.0f + e);
    return copysignf(r, z);
}

// VMEM-hygiene wave specialization. grid=256 (1 WG/CU), b=blk>>3 (spread
// mapping), q=blk&7 = 64-row slice. Waves (w=tid>>6, lane=tid&63):
//   w=0..6  : poll chunk ch(w) of h_i (ONLY global op: 1 tagged u64 load per
//             lane -> its vmcnt(0) covers nothing else), stage to LDS,
//             compute part[row=lane][w] over 64 cols, sdot (WG0), cnt++.
//   w=7     : owns chunk q (local, no polling). Computes its partial, spins
//             on cnt==8*(i+1), sums 8 partials + bias, tanh, publishes
//             tagged u64 (STORES ONLY — never waits vmcnt), writes own LDS
//             chunk for next step. WG0: sums sdot, counts score.
//   w=8     : x-loader. Streams x rows into 4-deep LDS ring, throttled by
//             cnt so it never overruns readers; bumps xflag.
// No __syncthreads in the loop. 2-parity global slots: overwrite of tag i+2
// is causally after every peer's detect of tag i (publish->poll chain), so
// 2 buffers suffice (same argument verified in R6).
__global__ __launch_bounds__(NTH, 1)
void rnn_seq(const float* __restrict__ x, const int* __restrict__ lengths,
             const float* __restrict__ W_ih, const float* __restrict__ W_hh,
             const float* __restrict__ b_ih, const float* __restrict__ b_hh,
             const float* __restrict__ W1, const float* __restrict__ b1,
             const float* __restrict__ W2, const float* __restrict__ b2,
             float* __restrict__ out, uint64_t* __restrict__ gbuf)
{
    const int blk  = blockIdx.x;
    const int b    = blk >> 3;      // batch (spread mapping — best R2/R4)
    const int q    = blk & 7;       // row slice
    const int tid  = threadIdx.x;
    const int w    = tid >> 6;      // wave role
    const int lane = tid & 63;
    const int len  = lengths[b];

    __shared__ float hs[2][8 * 68];        // [parity][chunk*68+j] (pad 4/64)
    __shared__ float part[2][64 * 9 + 8];  // [parity][row*9 + w]
    __shared__ float sdot[2][8];
    __shared__ float xbuf[4][FF];          // x ring, depth 4
    __shared__ int   cnt_s, xflag_s;

    // chunk owned by this wave: w<7 -> the 7 non-q chunks; w==7 -> q
    const int ch = (w == 7) ? q : (w + (w >= q ? 1 : 0));

    // ---- one-time init ----
    float4 ww[16], wi[4];
    float wvreg = 0.f, bias_r = 0.f, cconst = 0.f;
    if (w <= 7) {
        const int grow = q * 64 + lane;
        const float4* p4 = (const float4*)(W_hh + (size_t)grow * HH + ch * 64);
        #pragma unroll
        for (int k = 0; k < 16; ++k) ww[k] = p4[k];
        const float4* pi = (const float4*)(W_ih + grow * FF + ch * 16);
        #pragma unroll
        for (int k = 0; k < 4; ++k) wi[k] = pi[k];
        const int col = ch * 64 + lane;      // scorer weight for this lane
        float a = 0.f;
        #pragma unroll 8
        for (int f = 0; f < FCC; ++f) a += W2[f] * W1[f * HH + col];
        wvreg = a;
        if (w == 7) {
            bias_r = b_ih[grow] + b_hh[grow];
            if (lane == 0) {
                float s = 0.f;
                for (int f = 0; f < FCC; ++f) s += W2[f] * b1[f];
                cconst = s + b2[0];
            }
        }
    }
    if (tid == 0) { cnt_s = 0; xflag_s = 2; }
    if (tid < 512) hs[0][(tid >> 6) * 68 + (tid & 63)] = 0.f;   // h_0 = 0
    if (w == 8) {
        const float* xg = x + (size_t)b * TT * FF;
        float2 v0 = *(const float2*)(xg + 0 * FF + lane * 2);
        float2 v1 = *(const float2*)(xg + 1 * FF + lane * 2);   // T>=2 always
        *(float2*)&xbuf[0][lane * 2] = v0;
        *(float2*)&xbuf[1][lane * 2] = v1;
    }
    __syncthreads();   // one-time

    uint64_t* gs0 = gbuf + (size_t)b * HH;
    uint64_t* gs1 = gbuf + (size_t)(BB + b) * HH;

    // ======================= wave 8: x loader =======================
    if (w == 8) {
        const float* xg = x + (size_t)b * TT * FF;
        for (int i = 0; i < len; ++i) {
            if (i >= 2) {  // don't overwrite x_{i-2}'s slot before step i-2 done
                while (__hip_atomic_load(&cnt_s, __ATOMIC_RELAXED,
                                         __HIP_MEMORY_SCOPE_WORKGROUP) < 8 * (i - 1)) {}
            }
            const int tp = i + 2;
            if (tp < len) {
                float2 v = *(const float2*)(xg + (size_t)tp * FF + lane * 2);
                *(float2*)&xbuf[tp & 3][lane * 2] = v;
                wait_lgkm0();
            }
            if (lane == 0)
                __hip_atomic_store(&xflag_s, i + 3, __ATOMIC_RELAXED,
                                   __HIP_MEMORY_SCOPE_WORKGROUP);
        }
        return;   // no barriers after this point
    }

    // =================== waves 0-7: recurrence ======================
    float hn_prev = 0.f;   // wave7: own h_i[lane]
    int count = 0;         // wave7 lane0 (q==0)

    for (int i = 0; i < len; ++i) {
        const int p  = i & 1;
        const int pn = p ^ 1;
        uint64_t* gsp  = p  ? gs1 : gs0;
        uint64_t* gspn = pn ? gs1 : gs0;

        float hreg;
        if (w < 7) {
            if (i > 0) {
                uint64_t* pr = gsp + ch * 64 + lane;
                uint64_t u;
                do { u = __hip_atomic_load(pr, __ATOMIC_RELAXED,
                                           __HIP_MEMORY_SCOPE_AGENT); }
                while ((int)(u >> 32) != i);
                hreg = __uint_as_float((uint32_t)u);
                hs[p][ch * 68 + lane] = hreg;
                wait_lgkm0();
            } else hreg = 0.f;
        } else {
            hreg = hn_prev;   // own chunk already in hs[p] (finalize i-1 / init)
        }

        if (i >= 2) {   // x_0,x_1 preloaded
            while (__hip_atomic_load(&xflag_s, __ATOMIC_RELAXED,
                                     __HIP_MEMORY_SCOPE_WORKGROUP) < i + 1) {}
        }

        // ---- partial: row=lane over cols [ch*64, ch*64+64) + x chunk
        const float4* hq = (const float4*)&hs[p][ch * 68];
        const float4* xq = (const float4*)&xbuf[i & 3][ch * 16];
        float a0, a1, a2, a3;
        { float4 xv = xq[0]; a0 = wi[0].x*xv.x + wi[0].y*xv.y + wi[0].z*xv.z + wi[0].w*xv.w; }
        { float4 xv = xq[1]; a1 = wi[1].x*xv.x + wi[1].y*xv.y + wi[1].z*xv.z + wi[1].w*xv.w; }
        { float4 xv = xq[2]; a2 = wi[2].x*xv.x + wi[2].y*xv.y + wi[2].z*xv.z + wi[2].w*xv.w; }
        { float4 xv = xq[3]; a3 = wi[3].x*xv.x + wi[3].y*xv.y + wi[3].z*xv.z + wi[3].w*xv.w; }
        #pragma unroll
        for (int k = 0; k < 16; ++k) {
            float4 hk = hq[k];
            a0 += ww[k].x * hk.x; a1 += ww[k].y * hk.y;
            a2 += ww[k].z * hk.z; a3 += ww[k].w * hk.w;
        }
        part[p][lane * 9 + w] = (a0 + a1) + (a2 + a3);

        // ---- scorer element-product (WG0, i>=1): d = h_i[col]*wv[col]
        if (q == 0 && i > 0) {
            float d = hreg * wvreg;
            d += __shfl_xor(d, 1);  d += __shfl_xor(d, 2);
            d += __shfl_xor(d, 4);  d += __shfl_xor(d, 8);
            d += __shfl_xor(d, 16); d += __shfl_xor(d, 32);
            if (lane == 0) sdot[p][w] = d;
        }
        wait_lgkm0();                      // part (+sdot) visible before cnt
        if (lane == 0) atomicAdd(&cnt_s, 1);

        if (w == 7) {
            const int tgt = 8 * (i + 1);
            while (__hip_atomic_load(&cnt_s, __ATOMIC_RELAXED,
                                     __HIP_MEMORY_SCOPE_WORKGROUP) < tgt) {}
            const float* pp = &part[p][lane * 9];
            float s8 = bias_r + ((pp[0] + pp[1]) + (pp[2] + pp[3]))
                              + ((pp[4] + pp[5]) + (pp[6] + pp[7]));
            float hn = fast_tanh(s8);
            if (q == 0 && i > 0 && lane == 0) {
                float ss = cconst;
                #pragma unroll
                for (int k = 0; k < 8; ++k) ss += sdot[p][k];
                if (ss > 0.f) ++count;
            }
            hn_prev = hn;
            hs[pn][q * 68 + lane] = hn;    // own chunk for step i+1 (private)
            uint64_t pk = ((uint64_t)(uint32_t)(i + 1) << 32) |
                          (uint64_t)__float_as_uint(hn);
            __hip_atomic_store(gspn + q * 64 + lane, pk, __ATOMIC_RELAXED,
                               __HIP_MEMORY_SCOPE_AGENT);   // fire & forget
        }
    }

    // ---- outputs: WG q==0 scores h_len and writes out ----
    if (q == 0) {
        const int fp = len & 1;
        uint64_t* gsf = fp ? gs1 : gs0;
        if (w < 7) {
            uint64_t* pr = gsf + ch * 64 + lane;
            uint64_t u;
            do { u = __hip_atomic_load(pr, __ATOMIC_RELAXED,
                                       __HIP_MEMORY_SCOPE_AGENT); }
            while ((int)(u >> 32) != len);
            float hv = __uint_as_float((uint32_t)u);
            out[BB + b * HH + ch * 64 + lane] = hv;
            float d = hv * wvreg;
            d += __shfl_xor(d, 1);  d += __shfl_xor(d, 2);
            d += __shfl_xor(d, 4);  d += __shfl_xor(d, 8);
            d += __shfl_xor(d, 16); d += __shfl_xor(d, 32);
            if (lane == 0) sdot[fp][w] = d;
            wait_lgkm0();
            if (lane == 0) atomicAdd(&cnt_s, 1);
        } else if (w == 7) {
            out[BB + b * HH + q * 64 + lane] = hn_prev;   // chunk q (=0)
            float d = hn_prev * wvreg;
            d += __shfl_xor(d, 1);  d += __shfl_xor(d, 2);
            d += __shfl_xor(d, 4);  d += __shfl_xor(d, 8);
            d += __shfl_xor(d, 16); d += __shfl_xor(d, 32);
            if (lane == 0) {
                sdot[fp][7] = d;
                wait_lgkm0();
                while (__hip_atomic_load(&cnt_s, __ATOMIC_RELAXED,
                                         __HIP_MEMORY_SCOPE_WORKGROUP) < 8 * len + 7) {}
                float ss = cconst;
                #pragma unroll
                for (int k = 0; k < 8; ++k) ss += sdot[fp][k];
                if (ss > 0.f) ++count;
                out[b] = (float)count;
            }
        }
    }
}

extern "C" void kernel_launch(void* const* d_in, const int* in_sizes, int n_in,
                              void* d_out, int out_size, void* d_ws, size_t ws_size,
                              hipStream_t stream) {
    const float* x    = (const float*)d_in[0];
    const int*   lens = (const int*)d_in[1];
    const float* W_ih = (const float*)d_in[2];
    const float* W_hh = (const float*)d_in[3];
    const float* b_ih = (const float*)d_in[4];
    const float* b_hh = (const float*)d_in[5];
    const float* W1   = (const float*)d_in[6];
    const float* b1   = (const float*)d_in[7];
    const float* W2   = (const float*)d_in[8];
    const float* b2   = (const float*)d_in[9];
    float* out = (float*)d_out;
    uint64_t* gbuf = (uint64_t*)d_ws;   // 2 * 32 * 512 u64 = 256 KB

    ws_zero<<<dim3((2 * BB * HH) / 256), dim3(256), 0, stream>>>(gbuf);
    rnn_seq<<<dim3(BB * QW), dim3(NTH), 0, stream>>>(
        x, lens, W_ih, W_hh, b_ih, b_hh, W1, b1, W2, b2, out, gbuf);
}

// Round 8
// 2888.997 us; speedup vs baseline: 1.6649x; 1.0992x over previous
//
#include <hip/hip_runtime.h>
#include <math.h>
#include <stdint.h>

#define BB 32
#define TT 2048
#define FF 128
#define HH 512
#define FCC 128
#define QW 8
#define NTH 640   // 10 waves: 0-7 compute+add, 8 reader, 9 scorer (WG q==0 only)

#define SCALE_F     1073741824.0f          // 2^30 fixed-point scale
#define INV_SCALE_F (1.0f/1073741824.0f)
#define CNT_ONE     (1ull<<48)             // arrival counter increment
#define LOW_MASK    ((1ull<<48)-1ull)
#define BIAS_TOTAL  (1ll<<46)              // keeps low field positive: no carry into bit 48
#define BIAS_SHARE  (1ll<<43)              // BIAS_TOTAL / 8 (one share per WG, first use of each parity)

__global__ void ws_zero(uint64_t* g) {     // counters/tags must start at 0 (0xAA poison aliases)
    g[(size_t)blockIdx.x * blockDim.x + threadIdx.x] = 0ull;
}

__device__ __forceinline__ void wait_lgkm0() {
    asm volatile("s_waitcnt lgkmcnt(0)" ::: "memory");
}

__device__ __forceinline__ float fast_tanh(float z) {
    float ax = fabsf(z);
    float e  = __expf(-2.0f * ax);
    float r  = (1.0f - e) / (1.0f + e);
    return copysignf(r, z);
}

// IC-gather RNN. grid=256 (1 WG/CU), b=blk>>3, q=blk&7.
// Transposed ownership: WG q owns COLS [q*64,q*64+64) of W_hh (+ cols
// [q*16..+16) of W_ih/x) for ALL 512 rows. Per step i:
//   waves 0-7 (thread row r=w*64+lane): read h_i chunk from LDS (broadcast),
//     partial A = W_hh[r][own cols]·h + W_ih[r][own xcols]·x_i, fixed-point
//     delta vs same-parity 2 steps ago, ONE fire-and-forget
//     global_atomic_add((cnt=1)<<48 | delta) to slot[(i+1)&1][b][r].
//   wave 8: polls OWN 64 slots until counter==8*uses (tag+value in one u64,
//     single RT), decodes, +bias, tanh, writes LDS h (2-parity) + flag.
//   wave 7 extra: publishes chunk-dot of h_i (tagged u64) into 16-deep ring;
//     wave 9 (WG q==0) consumes ring, counts score>0, writes out[b].
// Parity-slot reuse safe: adds for use n+1 of buf P happen only after every
// WG read use n (read->flag->compute->add causality, as R6/R7). Carry-safe
// u64 packing: low field = 2^46 + A_i*2^30, |A|<2^9 -> field in
// [2^46-2^39, 2^46+2^39], never crosses 0 or 2^48.
__global__ __launch_bounds__(NTH, 1)
void rnn_seq(const float* __restrict__ x, const int* __restrict__ lengths,
             const float* __restrict__ W_ih, const float* __restrict__ W_hh,
             const float* __restrict__ b_ih, const float* __restrict__ b_hh,
             const float* __restrict__ W1, const float* __restrict__ b1,
             const float* __restrict__ W2, const float* __restrict__ b2,
             float* __restrict__ out, uint64_t* __restrict__ ws)
{
    const int blk  = blockIdx.x;
    const int b    = blk >> 3;      // batch (spread mapping)
    const int q    = blk & 7;       // col-chunk owned by this WG
    const int tid  = threadIdx.x;
    const int w    = tid >> 6;
    const int lane = tid & 63;
    const int len  = lengths[b];

    uint64_t* gh  = ws;                         // [2][BB][HH] row accumulators
    uint64_t* gsd = ws + 2 * BB * HH;           // [BB][16][8] scorer ring

    __shared__ float hsh[2][64];                // h chunk, 2-parity
    __shared__ float biass[64];
    __shared__ int   flag_s;                    // highest j with h_j in hsh[j&1]

    if (w == 8) {
        biass[lane] = b_ih[q * 64 + lane] + b_hh[q * 64 + lane];
        hsh[0][lane] = 0.0f;                    // h_0 = 0
        if (lane == 0) flag_s = 0;
    }
    __syncthreads();

    if (w < 8) {
        // ================= compute+add role: row r =================
        const int r = w * 64 + lane;
        float4 ww[16];
        { const float4* p = (const float4*)(W_hh + (size_t)r * HH + q * 64);
          #pragma unroll
          for (int k = 0; k < 16; ++k) ww[k] = p[k]; }
        float4 wi[4];
        { const float4* p = (const float4*)(W_ih + r * FF + q * 16);
          #pragma unroll
          for (int k = 0; k < 4; ++k) wi[k] = p[k]; }
        float wvreg = 0.0f;
        if (w == 7) {                           // scorer weight for col q*64+lane
            const int col = q * 64 + lane;
            #pragma unroll 8
            for (int f = 0; f < FCC; ++f) wvreg += W2[f] * W1[f * HH + col];
        }
        long long prevA[2] = {0, 0};
        const float* xb = x + (size_t)b * TT * FF + q * 16;
        float4 xc[4], xn[4];
        { const float4* p = (const float4*)xb;
          #pragma unroll
          for (int k = 0; k < 4; ++k) xc[k] = p[k]; }
        { const float4* p = (const float4*)(xb + FF);
          #pragma unroll
          for (int k = 0; k < 4; ++k) xn[k] = p[k]; }

        uint64_t* ghb = gh + (size_t)b * HH + r;

        for (int i = 0; i < len; ++i) {
            while (__hip_atomic_load(&flag_s, __ATOMIC_RELAXED,
                                     __HIP_MEMORY_SCOPE_WORKGROUP) < i) {}
            const float* hc = hsh[i & 1];
            const float4* hq = (const float4*)hc;
            float a0, a1, a2, a3;
            a0 = wi[0].x*xc[0].x + wi[0].y*xc[0].y + wi[0].z*xc[0].z + wi[0].w*xc[0].w;
            a1 = wi[1].x*xc[1].x + wi[1].y*xc[1].y + wi[1].z*xc[1].z + wi[1].w*xc[1].w;
            a2 = wi[2].x*xc[2].x + wi[2].y*xc[2].y + wi[2].z*xc[2].z + wi[2].w*xc[2].w;
            a3 = wi[3].x*xc[3].x + wi[3].y*xc[3].y + wi[3].z*xc[3].z + wi[3].w*xc[3].w;
            #pragma unroll
            for (int k = 0; k < 16; ++k) {
                float4 hk = hq[k];
                a0 += ww[k].x * hk.x; a1 += ww[k].y * hk.y;
                a2 += ww[k].z * hk.z; a3 += ww[k].w * hk.w;
            }
            float A = (a0 + a1) + (a2 + a3);

            float hown = 0.0f;
            if (w == 7) hown = hc[lane];        // capture h_i before add (dep-ordered by publish)

            long long f = llrintf(A * SCALE_F);
            const int pn = (i + 1) & 1;
            long long con = (long long)CNT_ONE + (f - prevA[pn])
                          + ((i < 2) ? BIAS_SHARE : 0);
            prevA[pn] = f;
            atomicAdd((unsigned long long*)(ghb + (size_t)pn * BB * HH),
                      (unsigned long long)con);          // fire-and-forget RMW

            if (w == 7 && i > 0) {              // scorer chunk-dot of h_i
                float d = hown * wvreg;
                d += __shfl_xor(d, 1);  d += __shfl_xor(d, 2);
                d += __shfl_xor(d, 4);  d += __shfl_xor(d, 8);
                d += __shfl_xor(d, 16); d += __shfl_xor(d, 32);
                if (lane == 0) {
                    uint64_t pk = ((uint64_t)(uint32_t)i << 32) |
                                  (uint64_t)__float_as_uint(d);
                    __hip_atomic_store(&gsd[((size_t)b * 16 + (i & 15)) * 8 + q],
                                       pk, __ATOMIC_RELAXED, __HIP_MEMORY_SCOPE_AGENT);
                }
            }
            #pragma unroll
            for (int k = 0; k < 4; ++k) xc[k] = xn[k];
            if (i + 2 < len) {
                const float4* p = (const float4*)(xb + (size_t)(i + 2) * FF);
                #pragma unroll
                for (int k = 0; k < 4; ++k) xn[k] = p[k];
            }
        }
        if (w == 7) {                            // final scorer dot: h_len
            while (__hip_atomic_load(&flag_s, __ATOMIC_RELAXED,
                                     __HIP_MEMORY_SCOPE_WORKGROUP) < len) {}
            float d = hsh[len & 1][lane] * wvreg;
            d += __shfl_xor(d, 1);  d += __shfl_xor(d, 2);
            d += __shfl_xor(d, 4);  d += __shfl_xor(d, 8);
            d += __shfl_xor(d, 16); d += __shfl_xor(d, 32);
            if (lane == 0) {
                uint64_t pk = ((uint64_t)(uint32_t)len << 32) |
                              (uint64_t)__float_as_uint(d);
                __hip_atomic_store(&gsd[((size_t)b * 16 + (len & 15)) * 8 + q],
                                   pk, __ATOMIC_RELAXED, __HIP_MEMORY_SCOPE_AGENT);
            }
        }
    } else if (w == 8) {
        // ================= reader role: own 64 slots =================
        float hval = 0.0f;
        for (int i = 0; i < len; ++i) {
            const int j  = i + 1;
            const int pn = j & 1;
            const uint64_t target = 8ull * (uint64_t)((j + 1) >> 1); // 8*uses of this parity
            uint64_t* pr = gh + (size_t)pn * BB * HH + (size_t)b * HH + q * 64 + lane;
            uint64_t u;
            do { u = __hip_atomic_load(pr, __ATOMIC_RELAXED,
                                       __HIP_MEMORY_SCOPE_AGENT); }
            while ((u >> 48) != target);
            long long sf = (long long)(u & LOW_MASK) - BIAS_TOTAL;
            float pre = (float)sf * INV_SCALE_F + biass[lane];
            hval = fast_tanh(pre);
            hsh[pn][lane] = hval;
            wait_lgkm0();
            if (lane == 0)
                __hip_atomic_store(&flag_s, j, __ATOMIC_RELAXED,
                                   __HIP_MEMORY_SCOPE_WORKGROUP);
        }
        out[BB + b * HH + q * 64 + lane] = hval;   // h_final chunk
    } else {
        // ================= scorer consumer (WG q==0 only) =================
        if (q != 0) return;
        float cconst = b2[0];
        for (int f = 0; f < FCC; ++f) cconst += W2[f] * b1[f];
        int count = 0;
        for (int j = 1; j <= len; ++j) {
            float d = 0.0f;
            if (lane < 8) {
                uint64_t* pr = gsd + ((size_t)b * 16 + (j & 15)) * 8 + lane;
                uint64_t u;
                do { u = __hip_atomic_load(pr, __ATOMIC_RELAXED,
                                           __HIP_MEMORY_SCOPE_AGENT); }
                while ((int)(u >> 32) != j);
                d = __uint_as_float((uint32_t)u);
            }
            d += __shfl_xor(d, 1); d += __shfl_xor(d, 2); d += __shfl_xor(d, 4);
            if (lane == 0 && d + cconst > 0.0f) ++count;
        }
        if (lane == 0) out[b] = (float)count;
    }
}

extern "C" void kernel_launch(void* const* d_in, const int* in_sizes, int n_in,
                              void* d_out, int out_size, void* d_ws, size_t ws_size,
                              hipStream_t stream) {
    const float* x    = (const float*)d_in[0];
    const int*   lens = (const int*)d_in[1];
    const float* W_ih = (const float*)d_in[2];
    const float* W_hh = (const float*)d_in[3];
    const float* b_ih = (const float*)d_in[4];
    const float* b_hh = (const float*)d_in[5];
    const float* W1   = (const float*)d_in[6];
    const float* b1   = (const float*)d_in[7];
    const float* W2   = (const float*)d_in[8];
    const float* b2   = (const float*)d_in[9];
    float* out = (float*)d_out;
    uint64_t* ws = (uint64_t*)d_ws;   // 2*32*512 + 32*16*8 = 36864 u64 = 288 KB

    ws_zero<<<dim3(144), dim3(256), 0, stream>>>(ws);
    rnn_seq<<<dim3(BB * QW), dim3(NTH), 0, stream>>>(
        x, lens, W_ih, W_hh, b_ih, b_hh, W1, b1, W2, b2, out, ws);
}